// Round 12
// baseline (41529.559 us; speedup 1.0000x reference)
//
#include <hip/hip_runtime.h>

// Problem constants
#define BB   64      // batch
#define TT   256     // seq len
#define II   768     // input dim
#define HH   384     // hidden per direction
#define DD   768     // 2*HH
#define G3   1152    // 3*HH
#define G6   2304    // both directions' gates

#define TILE 128
#define BK   16

typedef unsigned long long u64t;

// ---------------------------------------------------------------------------
// GEMM: gx[t][b][n] = bias[n] + sum_k X[t,b,k] * W[n,k]   (n in [0,2304))
// Natural layout: recurrence threads read n=col contiguously -> coalesced.
// xmode 0: X = Sentences [B][T][768]; xmode 1: X = [T*B][768] row-major.
// ---------------------------------------------------------------------------
__global__ __launch_bounds__(256) void gemm_gx(
    const float* __restrict__ X, int xmode,
    const float* __restrict__ wf, const float* __restrict__ wb,
    const float* __restrict__ bif, const float* __restrict__ bib,
    float* __restrict__ gx)
{
    __shared__ float As[BK][TILE + 4];
    __shared__ float Bs[BK][TILE + 4];
    const int tid = threadIdx.x;
    const int tx = tid & 15, ty = tid >> 4;
    const int m0 = blockIdx.y * TILE;
    const int n0 = blockIdx.x * TILE;

    float acc[8][8];
#pragma unroll
    for (int i = 0; i < 8; i++)
#pragma unroll
        for (int j = 0; j < 8; j++) acc[i][j] = 0.f;

    for (int k0 = 0; k0 < 768; k0 += BK) {
#pragma unroll
        for (int l = 0; l < 2; l++) {
            int id = tid + l * 256;          // 0..511
            int r  = id >> 2;                // 0..127
            int kq = (id & 3) * 4;
            int m  = m0 + r;
            const float* src;
            if (xmode == 0) {
                int b = m & 63, t = m >> 6;
                src = X + (size_t)b * (TT * II) + (size_t)t * II + k0 + kq;
            } else {
                src = X + (size_t)m * 768 + k0 + kq;
            }
            float4 v = *(const float4*)src;
            As[kq + 0][r] = v.x; As[kq + 1][r] = v.y;
            As[kq + 2][r] = v.z; As[kq + 3][r] = v.w;
        }
#pragma unroll
        for (int l = 0; l < 2; l++) {
            int id = tid + l * 256;
            int r  = id >> 2;
            int kq = (id & 3) * 4;
            int n  = n0 + r;
            const float* wsrc = (n < G3) ? (wf + (size_t)n * 768)
                                         : (wb + (size_t)(n - G3) * 768);
            float4 v = *(const float4*)(wsrc + k0 + kq);
            Bs[kq + 0][r] = v.x; Bs[kq + 1][r] = v.y;
            Bs[kq + 2][r] = v.z; Bs[kq + 3][r] = v.w;
        }
        __syncthreads();
#pragma unroll
        for (int kk = 0; kk < BK; ++kk) {
            float av[8], bv[8];
            *(float4*)&av[0] = *(const float4*)&As[kk][ty * 8];
            *(float4*)&av[4] = *(const float4*)&As[kk][ty * 8 + 4];
            *(float4*)&bv[0] = *(const float4*)&Bs[kk][tx * 8];
            *(float4*)&bv[4] = *(const float4*)&Bs[kk][tx * 8 + 4];
#pragma unroll
            for (int i = 0; i < 8; i++)
#pragma unroll
                for (int j = 0; j < 8; j++)
                    acc[i][j] = fmaf(av[i], bv[j], acc[i][j]);
        }
        __syncthreads();
    }

#pragma unroll
    for (int i = 0; i < 8; i++) {
        int m = m0 + ty * 8 + i;
        int t = m >> 6, b = m & 63;
        float* dst = gx + (size_t)t * (BB * G6) + (size_t)b * G6 + n0 + tx * 8;
#pragma unroll
        for (int j = 0; j < 8; j++) {
            int n = n0 + tx * 8 + j;
            float bias = (n < G3) ? bif[n] : bib[n - G3];
            dst[j] = acc[i][j] + bias;
        }
    }
}

// ---------------------------------------------------------------------------
// prep_w: pack w_hh fp32 [1152][384] -> bf16-pair u32, per-(col,ks)-
// contiguous: dst[(col*3+ks)*192 + q*4 + j], quad q: gate g=q%3, octet
// o=q/3; u32 j holds bf16 w[g*384+col][k0], w[..][k0+1], k0=ks*128+o*8+j*2.
// RTNE rounding.
// ---------------------------------------------------------------------------
__global__ __launch_bounds__(256) void prep_w(
    const float* __restrict__ w0f, const float* __restrict__ w0b,
    const float* __restrict__ w1f, const float* __restrict__ w1b,
    unsigned* __restrict__ p0f, unsigned* __restrict__ p0b,
    unsigned* __restrict__ p1f, unsigned* __restrict__ p1b)
{
    const int m = blockIdx.y;
    const float* src = (m == 0) ? w0f : (m == 1) ? w0b : (m == 2) ? w1f : w1b;
    unsigned*    dst = (m == 0) ? p0f : (m == 1) ? p0b : (m == 2) ? p1f : p1b;
    int i = blockIdx.x * 256 + threadIdx.x;
    if (i >= 384 * 576) return;
    int col = i / 576, r = i % 576;
    int ks  = r / 192, rr = r % 192;
    int q   = rr / 4,  j  = rr % 4;
    int g   = q % 3,   o  = q / 3;
    int k0  = ks * 128 + o * 8 + j * 2;
    int row = g * HH + col;
    unsigned a0 = __float_as_uint(src[(size_t)row * HH + k0]);
    unsigned a1 = __float_as_uint(src[(size_t)row * HH + k0 + 1]);
    a0 = (a0 + 0x7FFFu + ((a0 >> 16) & 1u)) >> 16;   // RTNE to bf16
    a1 = (a1 + 0x7FFFu + ((a1 >> 16) & 1u)) >> 16;
    dst[i] = a0 | (a1 << 16);
}

// ---------------------------------------------------------------------------
// Recurrent kernel v13: weights RESIDENT IN REGISTERS; 3 WGs per chain-set
// exchange h via the proven mantissa-tagged mailbox (v10 protocol).
//
// 192 WGs x 384 thr (cooperative). set = bid/3 = dir*32 + rowpair; WG owns
// cols c0=(bid%3)*128 .. +127 for batch rows {2*rp, 2*rp+1}. Thread
// (c=tid&127, ks=tid>>7): col c0+c, k-range [ks*128,(ks+1)*128); its 384
// bf16 weights = 48 uint4 in VGPRs (loaded once; static indices). Wave =
// one ks => LDS h reads are wave-uniform broadcasts.
//
// Per step: [stage] every thread spins 2 mailbox dwords (tag==s) into LDS
// h-buffer; barrier; [dots] 1152 VALU from reg-weights x LDS-h; partial ->
// LDS; barrier; [finalize, ks==0] 3-way k-sum + gate math + publish 2
// tagged dwords (tag=s+1) + out. Ping-pong race-freedom: a WG writes
// buffer pn at step s only after all WGs published step s (they passed
// their step-s-1 reads of pn). Tags: low 8 mantissa bits (rel err 2^-16).
// ---------------------------------------------------------------------------
__global__ __launch_bounds__(384, 2) void recur13(
    const float* __restrict__ gx,   // [T][B][2304] (b_ih already added)
    const unsigned* __restrict__ wpkf, const unsigned* __restrict__ wpkb,
    const float* __restrict__ bhf, const float* __restrict__ bhb,
    unsigned* __restrict__ mb,      // [64 set][2 pp][2 row][384] dw, zeroed
    float* __restrict__ out)        // [T][B][768]
{
    __shared__ float hb[2][2][HH];      // [pp][row][col] 6144 B
    __shared__ float part[128][2][7];   // ks=1,2 partials, padded: 7168 B

    const int bid = blockIdx.x;         // 0..191
    const int set = bid / 3;            // dir*32 + rp
    const int dir = set >> 5;
    const int rp  = set & 31;
    const int b0  = rp * 2;
    const int c0  = (bid % 3) * 128;
    const int tid = threadIdx.x;        // 0..383
    const int c   = tid & 127;
    const int ks  = tid >> 7;           // 0..2 (wave-uniform)
    const int col = c0 + c;

    // ---- weights -> registers (48 uint4, one-time coalesced-ish load)
    const unsigned* wp = (dir ? wpkb : wpkf) + ((size_t)col * 3 + ks) * 192;
    uint4 w4[48];
#pragma unroll
    for (int q = 0; q < 48; ++q) w4[q] = ((const uint4*)wp)[q];

    const float* bh = dir ? bhb : bhf;
    float bhr = 0.f, bhz = 0.f, bhn = 0.f;
    if (ks == 0) { bhr = bh[col]; bhz = bh[HH + col]; bhn = bh[2 * HH + col]; }
    float hp0 = 0.f, hp1 = 0.f;

    unsigned* mbs = mb + (size_t)set * 1536;   // [2pp][2row][384]
    const int kbase = ks * 128;

#pragma unroll 1
    for (int s = 0; s < TT; ++s) {
        const int t  = dir ? (TT - 1 - s) : s;
        const int pp = s & 1, pn = pp ^ 1;
        const unsigned want8 = (unsigned)s & 0xFFu;
        const unsigned tagp  = (unsigned)(s + 1) & 0xFFu;
        const unsigned* mbp = mbs + pp * 768;

        // gx loads (ks==0 finalizers): issue BEFORE the spin, used at end
        float gr0 = 0.f, gz0 = 0.f, gn0 = 0.f, gr1 = 0.f, gz1 = 0.f, gn1 = 0.f;
        if (ks == 0) {
            const float* g0 = gx + ((size_t)t * BB + b0) * G6 + dir * G3 + col;
            gr0 = g0[0]; gz0 = g0[HH]; gn0 = g0[2 * HH];
            const float* g1 = g0 + G6;
            gr1 = g1[0]; gz1 = g1[HH]; gn1 = g1[2 * HH];
        }

        // ---- stage: 2 tagged dwords per thread (rows 0,1 of col=tid)
        {
            unsigned v0, v1;
            for (;;) {
                v0 = __hip_atomic_load(mbp + tid, __ATOMIC_RELAXED,
                                       __HIP_MEMORY_SCOPE_AGENT);
                if ((v0 & 0xFFu) == want8) break;
                __builtin_amdgcn_s_sleep(1);
            }
            for (;;) {
                v1 = __hip_atomic_load(mbp + 384 + tid, __ATOMIC_RELAXED,
                                       __HIP_MEMORY_SCOPE_AGENT);
                if ((v1 & 0xFFu) == want8) break;
                __builtin_amdgcn_s_sleep(1);
            }
            hb[pp][0][tid] = __uint_as_float(v0);
            hb[pp][1][tid] = __uint_as_float(v1);
        }
        __syncthreads();

        // ---- dots: reg weights x LDS h (wave-uniform broadcast reads)
        float acc[6] = {0.f, 0.f, 0.f, 0.f, 0.f, 0.f};   // [gate*2+row]
#pragma unroll
        for (int o = 0; o < 16; ++o) {
            const float* hx = &hb[pp][0][kbase + o * 8];
            const float* hy = &hb[pp][1][kbase + o * 8];
            float4 x0 = *(const float4*)hx, x1 = *(const float4*)(hx + 4);
            float4 y0 = *(const float4*)hy, y1 = *(const float4*)(hy + 4);
            float hxv[8] = {x0.x, x0.y, x0.z, x0.w, x1.x, x1.y, x1.z, x1.w};
            float hyv[8] = {y0.x, y0.y, y0.z, y0.w, y1.x, y1.y, y1.z, y1.w};
#pragma unroll
            for (int g = 0; g < 3; ++g) {
                uint4 wq = w4[o * 3 + g];
                unsigned uu[4] = {wq.x, wq.y, wq.z, wq.w};
#pragma unroll
                for (int j = 0; j < 4; ++j) {
                    float wl = __uint_as_float(uu[j] << 16);
                    float wh = __uint_as_float(uu[j] & 0xFFFF0000u);
                    acc[g * 2 + 0] = fmaf(wl, hxv[j * 2],     acc[g * 2 + 0]);
                    acc[g * 2 + 0] = fmaf(wh, hxv[j * 2 + 1], acc[g * 2 + 0]);
                    acc[g * 2 + 1] = fmaf(wl, hyv[j * 2],     acc[g * 2 + 1]);
                    acc[g * 2 + 1] = fmaf(wh, hyv[j * 2 + 1], acc[g * 2 + 1]);
                }
            }
        }

        // ---- k-reduce via LDS (ks 1,2 write; padded stride 14 -> 2-way)
        if (ks != 0) {
#pragma unroll
            for (int i = 0; i < 6; ++i) part[c][ks - 1][i] = acc[i];
        }
        __syncthreads();

        // ---- finalize (ks==0): sum, gate math, publish, out
        if (ks == 0) {
#pragma unroll
            for (int i = 0; i < 6; ++i)
                acc[i] += part[c][0][i] + part[c][1][i];

            float ghr0 = acc[0] + bhr, ghr1 = acc[1] + bhr;
            float ghz0 = acc[2] + bhz, ghz1 = acc[3] + bhz;
            float ghn0 = acc[4] + bhn, ghn1 = acc[5] + bhn;

            float r0 = 1.f / (1.f + expf(-(gr0 + ghr0)));
            float z0 = 1.f / (1.f + expf(-(gz0 + ghz0)));
            float n0 = tanhf(gn0 + r0 * ghn0);
            float h0n = (1.f - z0) * n0 + z0 * hp0;
            hp0 = h0n;

            float r1 = 1.f / (1.f + expf(-(gr1 + ghr1)));
            float z1 = 1.f / (1.f + expf(-(gz1 + ghz1)));
            float n1 = tanhf(gn1 + r1 * ghn1);
            float h1n = (1.f - z1) * n1 + z1 * hp1;
            hp1 = h1n;

            unsigned* mbn = mbs + pn * 768;
            unsigned bits0 = (__float_as_uint(h0n) & 0xFFFFFF00u) | tagp;
            unsigned bits1 = (__float_as_uint(h1n) & 0xFFFFFF00u) | tagp;
            __hip_atomic_store(mbn + col, bits0, __ATOMIC_RELAXED,
                               __HIP_MEMORY_SCOPE_AGENT);
            __hip_atomic_store(mbn + 384 + col, bits1, __ATOMIC_RELAXED,
                               __HIP_MEMORY_SCOPE_AGENT);

            out[((size_t)t * BB + b0) * DD + dir * HH + col]     = h0n;
            out[((size_t)t * BB + b0 + 1) * DD + dir * HH + col] = h1n;
        }
    }
}

// ---------------------------------------------------------------------------
// Attention logits: logits[b][t] += sum_n tanh(hidden[t,b,:]·fcw[n,:] + fcb[n]) * upw[n]
// ---------------------------------------------------------------------------
__global__ __launch_bounds__(256) void attn_logits(
    const float* __restrict__ Xh,   // hidden [T*B][768]
    const float* __restrict__ fcw,  // [768][768]
    const float* __restrict__ fcb, const float* __restrict__ upw,
    float* __restrict__ logits)     // [B][T]
{
    __shared__ float As[BK][TILE + 4];
    __shared__ float Bs[BK][TILE + 4];
    __shared__ float red[TILE][17];
    const int tid = threadIdx.x;
    const int tx = tid & 15, ty = tid >> 4;
    const int m0 = blockIdx.y * TILE;
    const int n0 = blockIdx.x * TILE;

    float acc[8][8];
#pragma unroll
    for (int i = 0; i < 8; i++)
#pragma unroll
        for (int j = 0; j < 8; j++) acc[i][j] = 0.f;

    for (int k0 = 0; k0 < 768; k0 += BK) {
#pragma unroll
        for (int l = 0; l < 2; l++) {
            int id = tid + l * 256;
            int r  = id >> 2;
            int kq = (id & 3) * 4;
            float4 v = *(const float4*)(Xh + (size_t)(m0 + r) * 768 + k0 + kq);
            As[kq + 0][r] = v.x; As[kq + 1][r] = v.y;
            As[kq + 2][r] = v.z; As[kq + 3][r] = v.w;
        }
#pragma unroll
        for (int l = 0; l < 2; l++) {
            int id = tid + l * 256;
            int r  = id >> 2;
            int kq = (id & 3) * 4;
            float4 v = *(const float4*)(fcw + (size_t)(n0 + r) * 768 + k0 + kq);
            Bs[kq + 0][r] = v.x; Bs[kq + 1][r] = v.y;
            Bs[kq + 2][r] = v.z; Bs[kq + 3][r] = v.w;
        }
        __syncthreads();
#pragma unroll
        for (int kk = 0; kk < BK; ++kk) {
            float av[8], bv[8];
            *(float4*)&av[0] = *(const float4*)&As[kk][ty * 8];
            *(float4*)&av[4] = *(const float4*)&As[kk][ty * 8 + 4];
            *(float4*)&bv[0] = *(const float4*)&Bs[kk][tx * 8];
            *(float4*)&bv[4] = *(const float4*)&Bs[kk][tx * 8 + 4];
#pragma unroll
            for (int i = 0; i < 8; i++)
#pragma unroll
                for (int j = 0; j < 8; j++)
                    acc[i][j] = fmaf(av[i], bv[j], acc[i][j]);
        }
        __syncthreads();
    }

#pragma unroll
    for (int i = 0; i < 8; i++) {
        float p = 0.f;
#pragma unroll
        for (int jj = 0; jj < 8; jj++) {
            int n = n0 + tx * 8 + jj;
            p += tanhf(acc[i][jj] + fcb[n]) * upw[n];
        }
        red[ty * 8 + i][tx] = p;
    }
    __syncthreads();
    if (tid < TILE) {
        float s = 0.f;
#pragma unroll
        for (int xk = 0; xk < 16; xk++) s += red[tid][xk];
        int m = m0 + tid;
        int t = m >> 6, b = m & 63;
        atomicAdd(&logits[(size_t)b * TT + t], s);
    }
}

// ---------------------------------------------------------------------------
// Softmax over T per batch + weighted pooling
// ---------------------------------------------------------------------------
__global__ __launch_bounds__(256) void softmax_pool(
    const float* __restrict__ logits, const float* __restrict__ upwb,
    const float* __restrict__ hidden, float* __restrict__ out)
{
    const int b = blockIdx.x, tid = threadIdx.x;
    __shared__ float sa[256];
    __shared__ float red[256];

    float l = logits[(size_t)b * TT + tid] + upwb[0];
    red[tid] = l; __syncthreads();
    for (int s = 128; s > 0; s >>= 1) {
        if (tid < s) red[tid] = fmaxf(red[tid], red[tid + s]);
        __syncthreads();
    }
    float mx = red[0];
    __syncthreads();
    float e = expf(l - mx);
    sa[tid] = e; red[tid] = e; __syncthreads();
    for (int s = 128; s > 0; s >>= 1) {
        if (tid < s) red[tid] += red[tid + s];
        __syncthreads();
    }
    float inv = 1.f / red[0];

    float o0 = 0.f, o1 = 0.f, o2 = 0.f;
    for (int t = 0; t < TT; t++) {
        float a = sa[t] * inv;
        const float* hp = hidden + (size_t)t * (BB * DD) + (size_t)b * DD;
        o0 = fmaf(a, hp[tid],       o0);
        o1 = fmaf(a, hp[tid + 256], o1);
        o2 = fmaf(a, hp[tid + 512], o2);
    }
    out[(size_t)b * DD + tid]       = o0;
    out[(size_t)b * DD + tid + 256] = o1;
    out[(size_t)b * DD + tid + 512] = o2;
}

// ---------------------------------------------------------------------------
extern "C" void kernel_launch(void* const* d_in, const int* in_sizes, int n_in,
                              void* d_out, int out_size, void* d_ws, size_t ws_size,
                              hipStream_t stream)
{
    const float* S        = (const float*)d_in[0];
    const float* w_ih_l0f = (const float*)d_in[1];
    const float* w_hh_l0f = (const float*)d_in[2];
    const float* b_ih_l0f = (const float*)d_in[3];
    const float* b_hh_l0f = (const float*)d_in[4];
    const float* w_ih_l0b = (const float*)d_in[5];
    const float* w_hh_l0b = (const float*)d_in[6];
    const float* b_ih_l0b = (const float*)d_in[7];
    const float* b_hh_l0b = (const float*)d_in[8];
    const float* w_ih_l1f = (const float*)d_in[9];
    const float* w_hh_l1f = (const float*)d_in[10];
    const float* b_ih_l1f = (const float*)d_in[11];
    const float* b_hh_l1f = (const float*)d_in[12];
    const float* w_ih_l1b = (const float*)d_in[13];
    const float* w_hh_l1b = (const float*)d_in[14];
    const float* b_ih_l1b = (const float*)d_in[15];
    const float* b_hh_l1b = (const float*)d_in[16];
    const float* fc_w     = (const float*)d_in[17];
    const float* fc_b     = (const float*)d_in[18];
    const float* upw_w    = (const float*)d_in[19];
    const float* upw_b    = (const float*)d_in[20];

    // workspace layout
    float* gx      = (float*)d_ws;                       // 256*64*2304 f
    float* buf2    = gx   + (size_t)TT * BB * G6;        // 256*64*768 f
    unsigned* p0f  = (unsigned*)(buf2 + (size_t)TT * BB * DD);  // 221184 each
    unsigned* p0b  = p0f + 221184;
    unsigned* p1f  = p0b + 221184;
    unsigned* p1b  = p1f + 221184;
    unsigned* mb0  = p1b + 221184;                       // 64*2*768 = 98304
    unsigned* mb1  = mb0 + 98304;                        // 98304
    float* logits  = (float*)(mb1 + 98304);              // 16384

    // zero mailboxes (both layers) + logits, every call (graph-replay safe)
    hipMemsetAsync(mb0, 0, (size_t)(2 * 98304 + 16384) * 4, stream);

    // pack all 4 w_hh matrices to bf16 pairs (one-time per call, ~30 us)
    prep_w<<<dim3(864, 4), 256, 0, stream>>>(w_hh_l0f, w_hh_l0b, w_hh_l1f, w_hh_l1b,
                                             p0f, p0b, p1f, p1b);

    // layer 0 input gates
    gemm_gx<<<dim3(18, 128), 256, 0, stream>>>(S, 0, w_ih_l0f, w_ih_l0b,
                                               b_ih_l0f, b_ih_l0b, gx);
    // layer 0 recurrence -> buf2
    {
        void* args[] = {(void*)&gx, (void*)&p0f, (void*)&p0b,
                        (void*)&b_hh_l0f, (void*)&b_hh_l0b, (void*)&mb0,
                        (void*)&buf2};
        hipLaunchCooperativeKernel((const void*)recur13, dim3(192), dim3(384),
                                   args, 0, stream);
    }
    // layer 1 input gates (from buf2)
    gemm_gx<<<dim3(18, 128), 256, 0, stream>>>(buf2, 1, w_ih_l1f, w_ih_l1b,
                                               b_ih_l1f, b_ih_l1b, gx);
    // layer 1 recurrence -> buf2 (separate pre-zeroed mailbox)
    {
        void* args[] = {(void*)&gx, (void*)&p1f, (void*)&p1b,
                        (void*)&b_hh_l1f, (void*)&b_hh_l1b, (void*)&mb1,
                        (void*)&buf2};
        hipLaunchCooperativeKernel((const void*)recur13, dim3(192), dim3(384),
                                   args, 0, stream);
    }
    // attention logits + pooling
    attn_logits<<<dim3(6, 128), 256, 0, stream>>>(buf2, fc_w, fc_b, upw_w, logits);
    softmax_pool<<<64, 256, 0, stream>>>(logits, upw_b, buf2, (float*)d_out);
}

// Round 13
// 6998.615 us; speedup vs baseline: 5.9340x; 5.9340x over previous
//
#include <hip/hip_runtime.h>

// Problem constants
#define BB   64      // batch
#define TT   256     // seq len
#define II   768     // input dim
#define HH   384     // hidden per direction
#define DD   768     // 2*HH
#define G3   1152    // 3*HH
#define G6   2304    // both directions' gates

#define TILE 128
#define BK   16

// ---------------------------------------------------------------------------
// GEMM: gx[t][b][n] = bias[n] + sum_k X[t,b,k] * W[n,k]   (n in [0,2304))
// Natural layout: recurrence threads read n=col contiguously -> coalesced.
// xmode 0: X = Sentences [B][T][768]; xmode 1: X = [T*B][768] row-major.
// ---------------------------------------------------------------------------
__global__ __launch_bounds__(256) void gemm_gx(
    const float* __restrict__ X, int xmode,
    const float* __restrict__ wf, const float* __restrict__ wb,
    const float* __restrict__ bif, const float* __restrict__ bib,
    float* __restrict__ gx)
{
    __shared__ float As[BK][TILE + 4];
    __shared__ float Bs[BK][TILE + 4];
    const int tid = threadIdx.x;
    const int tx = tid & 15, ty = tid >> 4;
    const int m0 = blockIdx.y * TILE;
    const int n0 = blockIdx.x * TILE;

    float acc[8][8];
#pragma unroll
    for (int i = 0; i < 8; i++)
#pragma unroll
        for (int j = 0; j < 8; j++) acc[i][j] = 0.f;

    for (int k0 = 0; k0 < 768; k0 += BK) {
#pragma unroll
        for (int l = 0; l < 2; l++) {
            int id = tid + l * 256;          // 0..511
            int r  = id >> 2;                // 0..127
            int kq = (id & 3) * 4;
            int m  = m0 + r;
            const float* src;
            if (xmode == 0) {
                int b = m & 63, t = m >> 6;
                src = X + (size_t)b * (TT * II) + (size_t)t * II + k0 + kq;
            } else {
                src = X + (size_t)m * 768 + k0 + kq;
            }
            float4 v = *(const float4*)src;
            As[kq + 0][r] = v.x; As[kq + 1][r] = v.y;
            As[kq + 2][r] = v.z; As[kq + 3][r] = v.w;
        }
#pragma unroll
        for (int l = 0; l < 2; l++) {
            int id = tid + l * 256;
            int r  = id >> 2;
            int kq = (id & 3) * 4;
            int n  = n0 + r;
            const float* wsrc = (n < G3) ? (wf + (size_t)n * 768)
                                         : (wb + (size_t)(n - G3) * 768);
            float4 v = *(const float4*)(wsrc + k0 + kq);
            Bs[kq + 0][r] = v.x; Bs[kq + 1][r] = v.y;
            Bs[kq + 2][r] = v.z; Bs[kq + 3][r] = v.w;
        }
        __syncthreads();
#pragma unroll
        for (int kk = 0; kk < BK; ++kk) {
            float av[8], bv[8];
            *(float4*)&av[0] = *(const float4*)&As[kk][ty * 8];
            *(float4*)&av[4] = *(const float4*)&As[kk][ty * 8 + 4];
            *(float4*)&bv[0] = *(const float4*)&Bs[kk][tx * 8];
            *(float4*)&bv[4] = *(const float4*)&Bs[kk][tx * 8 + 4];
#pragma unroll
            for (int i = 0; i < 8; i++)
#pragma unroll
                for (int j = 0; j < 8; j++)
                    acc[i][j] = fmaf(av[i], bv[j], acc[i][j]);
        }
        __syncthreads();
    }

#pragma unroll
    for (int i = 0; i < 8; i++) {
        int m = m0 + ty * 8 + i;
        int t = m >> 6, b = m & 63;
        float* dst = gx + (size_t)t * (BB * G6) + (size_t)b * G6 + n0 + tx * 8;
#pragma unroll
        for (int j = 0; j < 8; j++) {
            int n = n0 + tx * 8 + j;
            float bias = (n < G3) ? bif[n] : bib[n - G3];
            dst[j] = acc[i][j] + bias;
        }
    }
}

// ---------------------------------------------------------------------------
// prep_w: pack w_hh fp32 [1152][384] -> bf16-pair u32 in WAVE-COALESCED
// layout: dst[(((ks*12 + blk)*6 + q4)*384 + c)*4 + j]
//   thread (c, ks) at block blk loads uint4 q4 = u32s q = q4*4+j;
//   q -> gate g = q/8, u = q%8; k = ks*192 + blk*16 + u*2; row = g*384+c.
// Consecutive c -> consecutive uint4 -> 1KB contiguous per wave load.
// RTNE rounding.
// ---------------------------------------------------------------------------
__global__ __launch_bounds__(256) void prep_w(
    const float* __restrict__ w0f, const float* __restrict__ w0b,
    const float* __restrict__ w1f, const float* __restrict__ w1b,
    unsigned* __restrict__ p0f, unsigned* __restrict__ p0b,
    unsigned* __restrict__ p1f, unsigned* __restrict__ p1b)
{
    const int m = blockIdx.y;
    const float* src = (m == 0) ? w0f : (m == 1) ? w0b : (m == 2) ? w1f : w1b;
    unsigned*    dst = (m == 0) ? p0f : (m == 1) ? p0b : (m == 2) ? p1f : p1b;
    int i = blockIdx.x * 256 + threadIdx.x;
    if (i >= 384 * 576) return;               // 221184 u32 per matrix
    int j    = i & 3;
    int tmp  = i >> 2;
    int c    = tmp % 384;
    int tmp2 = tmp / 384;
    int q4   = tmp2 % 6;
    int tmp3 = tmp2 / 6;
    int blk  = tmp3 % 12;
    int ks   = tmp3 / 12;
    int q    = q4 * 4 + j;
    int g    = q >> 3;
    int u    = q & 7;
    int k0   = ks * 192 + blk * 16 + u * 2;
    int row  = g * HH + c;
    unsigned a0 = __float_as_uint(src[(size_t)row * HH + k0]);
    unsigned a1 = __float_as_uint(src[(size_t)row * HH + k0 + 1]);
    a0 = (a0 + 0x7FFFu + ((a0 >> 16) & 1u)) >> 16;   // RTNE to bf16
    a1 = (a1 + 0x7FFFu + ((a1 >> 16) & 1u)) >> 16;
    dst[i] = a0 | (a1 << 16);
}

// ---------------------------------------------------------------------------
// Recurrent kernel v14: zero inter-WG communication (v12 structure) with the
// weight stream fixed: 768 thr/WG (12 waves -> 3/SIMD latency hiding),
// wave-coalesced packed-weight loads, wave-uniform (broadcast) LDS h reads.
//
// 64 WGs x 768 thr. WG = (dir = bid&1, batch rows {2*(bid>>1), +1}).
// Thread (c = tid%384, ks = tid/384): column c, k-half [ks*192,(ks+1)*192).
// Per step: dots from hb[pp] (1152 FMA/thread) with weights streamed from
// L2; ks==1 writes partials; barrier; ks==0 reduces + gate math + writes
// hb[pn] + out; barrier. No spins, no flags, plain launch.
// ---------------------------------------------------------------------------
__device__ __forceinline__ void accq(uint4 W, const float* hx, const float* hy,
                                     int o, float& a0, float& a1)
{
    unsigned uu[4] = {W.x, W.y, W.z, W.w};
#pragma unroll
    for (int j = 0; j < 4; ++j) {
        float wl = __uint_as_float(uu[j] << 16);
        float wh = __uint_as_float(uu[j] & 0xFFFF0000u);
        a0 = fmaf(wl, hx[(o + j) * 2],     a0);
        a0 = fmaf(wh, hx[(o + j) * 2 + 1], a0);
        a1 = fmaf(wl, hy[(o + j) * 2],     a1);
        a1 = fmaf(wh, hy[(o + j) * 2 + 1], a1);
    }
}

__global__ __launch_bounds__(768, 4) void recur14(
    const float* __restrict__ gx,   // [T][B][2304] (b_ih already added)
    const unsigned* __restrict__ wpf, const unsigned* __restrict__ wpb,
    const float* __restrict__ bhf, const float* __restrict__ bhb,
    float* __restrict__ out)        // [T][B][768]
{
    __shared__ float hb[2][2][HH];      // [pp][row][col] 6144 B
    __shared__ float part[HH][7];       // ks=1 partials, stride-7 pad: 10752 B

    const int bid = blockIdx.x;         // 0..63
    const int dir = bid & 1;
    const int b0  = (bid >> 1) * 2;     // this WG's 2 batch rows
    const int tid = threadIdx.x;        // 0..767
    const int c   = tid % 384;          // hidden column
    const int ks  = tid / 384;          // k-half (wave-uniform: waves 0-5 / 6-11)

    const uint4* w4 = (const uint4*)((dir ? wpb : wpf)) + (size_t)ks * 12 * 6 * 384;
    const float* bh = dir ? bhb : bhf;
    float bhr = 0.f, bhz = 0.f, bhn = 0.f;
    if (ks == 0) { bhr = bh[c]; bhz = bh[HH + c]; bhn = bh[2 * HH + c]; }
    float hp0 = 0.f, hp1 = 0.f;

    if (ks == 0) { hb[0][0][c] = 0.f; hb[0][1][c] = 0.f; }
    __syncthreads();

    const int kb = ks * 192;

#pragma unroll 1
    for (int s = 0; s < TT; ++s) {
        const int t  = dir ? (TT - 1 - s) : s;
        const int pp = s & 1, pn = pp ^ 1;

        // gx loads (ks==0 only): issued at step top, consumed in finalize
        float gr0 = 0.f, gz0 = 0.f, gn0 = 0.f, gr1 = 0.f, gz1 = 0.f, gn1 = 0.f;
        if (ks == 0) {
            const float* g0 = gx + ((size_t)t * BB + b0) * G6 + dir * G3 + c;
            gr0 = g0[0]; gz0 = g0[HH]; gn0 = g0[2 * HH];
            const float* g1 = g0 + G6;
            gr1 = g1[0]; gz1 = g1[HH]; gn1 = g1[2 * HH];
        }

        // ---- dots over my 192 k (12 blocks of 16), weights from L2
        float ar0 = 0.f, ar1 = 0.f, az0 = 0.f, az1 = 0.f, an0 = 0.f, an1 = 0.f;
#pragma unroll 2
        for (int blk = 0; blk < 12; ++blk) {
            const uint4* wbp = w4 + (size_t)blk * 6 * 384 + c;
            uint4 W0 = wbp[0 * 384];     // gate r, k 0..7  (coalesced)
            uint4 W1 = wbp[1 * 384];     // gate r, k 8..15
            uint4 W2 = wbp[2 * 384];     // gate z, k 0..7
            uint4 W3 = wbp[3 * 384];     // gate z, k 8..15
            uint4 W4 = wbp[4 * 384];     // gate n, k 0..7
            uint4 W5 = wbp[5 * 384];     // gate n, k 8..15

            const float* hx = &hb[pp][0][kb + blk * 16];  // wave-uniform addr
            const float* hy = &hb[pp][1][kb + blk * 16];  // -> broadcast reads

            accq(W0, hx, hy, 0, ar0, ar1);
            accq(W1, hx, hy, 4, ar0, ar1);
            accq(W2, hx, hy, 0, az0, az1);
            accq(W3, hx, hy, 4, az0, az1);
            accq(W4, hx, hy, 0, an0, an1);
            accq(W5, hx, hy, 4, an0, an1);
        }

        // ---- ks==1: hand partials to ks==0 (stride-7 = conflict-free)
        if (ks == 1) {
            part[c][0] = ar0; part[c][1] = ar1;
            part[c][2] = az0; part[c][3] = az1;
            part[c][4] = an0; part[c][5] = an1;
        }
        __syncthreads();

        // ---- finalize (ks==0): reduce, gate math, write hb[pn] + out
        if (ks == 0) {
            ar0 += part[c][0]; ar1 += part[c][1];
            az0 += part[c][2]; az1 += part[c][3];
            an0 += part[c][4]; an1 += part[c][5];

            float ghr0 = ar0 + bhr, ghz0 = az0 + bhz, ghn0 = an0 + bhn;
            float r0 = 1.f / (1.f + expf(-(gr0 + ghr0)));
            float z0 = 1.f / (1.f + expf(-(gz0 + ghz0)));
            float n0 = tanhf(gn0 + r0 * ghn0);
            float h0n = (1.f - z0) * n0 + z0 * hp0;
            hp0 = h0n;

            float ghr1 = ar1 + bhr, ghz1 = az1 + bhz, ghn1 = an1 + bhn;
            float r1 = 1.f / (1.f + expf(-(gr1 + ghr1)));
            float z1 = 1.f / (1.f + expf(-(gz1 + ghz1)));
            float n1 = tanhf(gn1 + r1 * ghn1);
            float h1n = (1.f - z1) * n1 + z1 * hp1;
            hp1 = h1n;

            hb[pn][0][c] = h0n;
            hb[pn][1][c] = h1n;
            out[((size_t)t * BB + b0) * DD + dir * HH + c]     = h0n;
            out[((size_t)t * BB + b0 + 1) * DD + dir * HH + c] = h1n;
        }
        __syncthreads();
    }
}

// ---------------------------------------------------------------------------
// Attention logits: logits[b][t] += sum_n tanh(hidden[t,b,:]·fcw[n,:] + fcb[n]) * upw[n]
// ---------------------------------------------------------------------------
__global__ __launch_bounds__(256) void attn_logits(
    const float* __restrict__ Xh,   // hidden [T*B][768]
    const float* __restrict__ fcw,  // [768][768]
    const float* __restrict__ fcb, const float* __restrict__ upw,
    float* __restrict__ logits)     // [B][T]
{
    __shared__ float As[BK][TILE + 4];
    __shared__ float Bs[BK][TILE + 4];
    __shared__ float red[TILE][17];
    const int tid = threadIdx.x;
    const int tx = tid & 15, ty = tid >> 4;
    const int m0 = blockIdx.y * TILE;
    const int n0 = blockIdx.x * TILE;

    float acc[8][8];
#pragma unroll
    for (int i = 0; i < 8; i++)
#pragma unroll
        for (int j = 0; j < 8; j++) acc[i][j] = 0.f;

    for (int k0 = 0; k0 < 768; k0 += BK) {
#pragma unroll
        for (int l = 0; l < 2; l++) {
            int id = tid + l * 256;
            int r  = id >> 2;
            int kq = (id & 3) * 4;
            float4 v = *(const float4*)(Xh + (size_t)(m0 + r) * 768 + k0 + kq);
            As[kq + 0][r] = v.x; As[kq + 1][r] = v.y;
            As[kq + 2][r] = v.z; As[kq + 3][r] = v.w;
        }
#pragma unroll
        for (int l = 0; l < 2; l++) {
            int id = tid + l * 256;
            int r  = id >> 2;
            int kq = (id & 3) * 4;
            float4 v = *(const float4*)(fcw + (size_t)(n0 + r) * 768 + k0 + kq);
            Bs[kq + 0][r] = v.x; Bs[kq + 1][r] = v.y;
            Bs[kq + 2][r] = v.z; Bs[kq + 3][r] = v.w;
        }
        __syncthreads();
#pragma unroll
        for (int kk = 0; kk < BK; ++kk) {
            float av[8], bv[8];
            *(float4*)&av[0] = *(const float4*)&As[kk][ty * 8];
            *(float4*)&av[4] = *(const float4*)&As[kk][ty * 8 + 4];
            *(float4*)&bv[0] = *(const float4*)&Bs[kk][tx * 8];
            *(float4*)&bv[4] = *(const float4*)&Bs[kk][tx * 8 + 4];
#pragma unroll
            for (int i = 0; i < 8; i++)
#pragma unroll
                for (int j = 0; j < 8; j++)
                    acc[i][j] = fmaf(av[i], bv[j], acc[i][j]);
        }
        __syncthreads();
    }

#pragma unroll
    for (int i = 0; i < 8; i++) {
        float p = 0.f;
#pragma unroll
        for (int jj = 0; jj < 8; jj++) {
            int n = n0 + tx * 8 + jj;
            p += tanhf(acc[i][jj] + fcb[n]) * upw[n];
        }
        red[ty * 8 + i][tx] = p;
    }
    __syncthreads();
    if (tid < TILE) {
        float s = 0.f;
#pragma unroll
        for (int xk = 0; xk < 16; xk++) s += red[tid][xk];
        int m = m0 + tid;
        int t = m >> 6, b = m & 63;
        atomicAdd(&logits[(size_t)b * TT + t], s);
    }
}

// ---------------------------------------------------------------------------
// Softmax over T per batch + weighted pooling
// ---------------------------------------------------------------------------
__global__ __launch_bounds__(256) void softmax_pool(
    const float* __restrict__ logits, const float* __restrict__ upwb,
    const float* __restrict__ hidden, float* __restrict__ out)
{
    const int b = blockIdx.x, tid = threadIdx.x;
    __shared__ float sa[256];
    __shared__ float red[256];

    float l = logits[(size_t)b * TT + tid] + upwb[0];
    red[tid] = l; __syncthreads();
    for (int s = 128; s > 0; s >>= 1) {
        if (tid < s) red[tid] = fmaxf(red[tid], red[tid + s]);
        __syncthreads();
    }
    float mx = red[0];
    __syncthreads();
    float e = expf(l - mx);
    sa[tid] = e; red[tid] = e; __syncthreads();
    for (int s = 128; s > 0; s >>= 1) {
        if (tid < s) red[tid] += red[tid + s];
        __syncthreads();
    }
    float inv = 1.f / red[0];

    float o0 = 0.f, o1 = 0.f, o2 = 0.f;
    for (int t = 0; t < TT; t++) {
        float a = sa[t] * inv;
        const float* hp = hidden + (size_t)t * (BB * DD) + (size_t)b * DD;
        o0 = fmaf(a, hp[tid],       o0);
        o1 = fmaf(a, hp[tid + 256], o1);
        o2 = fmaf(a, hp[tid + 512], o2);
    }
    out[(size_t)b * DD + tid]       = o0;
    out[(size_t)b * DD + tid + 256] = o1;
    out[(size_t)b * DD + tid + 512] = o2;
}

// ---------------------------------------------------------------------------
extern "C" void kernel_launch(void* const* d_in, const int* in_sizes, int n_in,
                              void* d_out, int out_size, void* d_ws, size_t ws_size,
                              hipStream_t stream)
{
    const float* S        = (const float*)d_in[0];
    const float* w_ih_l0f = (const float*)d_in[1];
    const float* w_hh_l0f = (const float*)d_in[2];
    const float* b_ih_l0f = (const float*)d_in[3];
    const float* b_hh_l0f = (const float*)d_in[4];
    const float* w_ih_l0b = (const float*)d_in[5];
    const float* w_hh_l0b = (const float*)d_in[6];
    const float* b_ih_l0b = (const float*)d_in[7];
    const float* b_hh_l0b = (const float*)d_in[8];
    const float* w_ih_l1f = (const float*)d_in[9];
    const float* w_hh_l1f = (const float*)d_in[10];
    const float* b_ih_l1f = (const float*)d_in[11];
    const float* b_hh_l1f = (const float*)d_in[12];
    const float* w_ih_l1b = (const float*)d_in[13];
    const float* w_hh_l1b = (const float*)d_in[14];
    const float* b_ih_l1b = (const float*)d_in[15];
    const float* b_hh_l1b = (const float*)d_in[16];
    const float* fc_w     = (const float*)d_in[17];
    const float* fc_b     = (const float*)d_in[18];
    const float* upw_w    = (const float*)d_in[19];
    const float* upw_b    = (const float*)d_in[20];

    // workspace layout
    float* gx      = (float*)d_ws;                       // 256*64*2304 f
    float* buf2    = gx   + (size_t)TT * BB * G6;        // 256*64*768 f
    unsigned* p0f  = (unsigned*)(buf2 + (size_t)TT * BB * DD);  // 221184 u32 each
    unsigned* p0b  = p0f + 221184;
    unsigned* p1f  = p0b + 221184;
    unsigned* p1b  = p1f + 221184;
    float* logits  = (float*)(p1b + 221184);             // 64*256 f

    // zero logits (attn uses atomicAdd)
    hipMemsetAsync(logits, 0, (size_t)BB * TT * sizeof(float), stream);

    // pack all 4 w_hh matrices to coalesced bf16 pairs (~30 us)
    prep_w<<<dim3(864, 4), 256, 0, stream>>>(w_hh_l0f, w_hh_l0b, w_hh_l1f, w_hh_l1b,
                                             p0f, p0b, p1f, p1b);

    // layer 0 input gates
    gemm_gx<<<dim3(18, 128), 256, 0, stream>>>(S, 0, w_ih_l0f, w_ih_l0b,
                                               b_ih_l0f, b_ih_l0b, gx);
    // layer 0 recurrence -> buf2 (plain launch, independent WGs)
    recur14<<<64, 768, 0, stream>>>(gx, p0f, p0b, b_hh_l0f, b_hh_l0b, buf2);

    // layer 1 input gates (from buf2)
    gemm_gx<<<dim3(18, 128), 256, 0, stream>>>(buf2, 1, w_ih_l1f, w_ih_l1b,
                                               b_ih_l1f, b_ih_l1b, gx);
    // layer 1 recurrence -> buf2
    recur14<<<64, 768, 0, stream>>>(gx, p1f, p1b, b_hh_l1f, b_hh_l1b, buf2);

    // attention logits + pooling
    attn_logits<<<dim3(6, 128), 256, 0, stream>>>(buf2, fc_w, fc_b, upw_w, logits);
    softmax_pool<<<64, 256, 0, stream>>>(logits, upw_b, buf2, (float*)d_out);
}